// Round 7
// baseline (586.133 us; speedup 1.0000x reference)
//
#include <hip/hip_runtime.h>
#include <hip/hip_bf16.h>
#include <cmath>

#define NB 8
#define CCH 8
#define FF 257
#define TT 1000
#define AD 512
#define EPSI 1.1920928955078125e-07f
#define EPS5 1e-05f

// pair indexing for Hermitian upper triangle (i<=j)
__host__ __device__ constexpr int PIDX(int i, int j) { return i * 8 - i * (i - 1) / 2 + (j - i); }        // 0..35
__host__ __device__ constexpr int QIDX(int i, int j) { return i * 7 - i * (i - 1) / 2 + (j - i - 1); }    // 0..27 (j>i)

// e -> (i,j) tables for the two triangles (compile-time folded in unrolled loops)
__device__ constexpr int RI_[36] = {0,0,0,0,0,0,0,0, 1,1,1,1,1,1,1, 2,2,2,2,2,2, 3,3,3,3,3, 4,4,4,4, 5,5,5, 6,6, 7};
__device__ constexpr int RJ_[36] = {0,1,2,3,4,5,6,7, 1,2,3,4,5,6,7, 2,3,4,5,6,7, 3,4,5,6,7, 4,5,6,7, 5,6,7, 6,7, 7};
__device__ constexpr int QI_[28] = {0,0,0,0,0,0,0, 1,1,1,1,1,1, 2,2,2,2,2, 3,3,3,3, 4,4,4, 5,5, 6};
__device__ constexpr int QJ_[28] = {1,2,3,4,5,6,7, 2,3,4,5,6,7, 3,4,5,6,7, 4,5,6,7, 5,6,7, 6,7, 7};

// final record layout per (n,f), stride 132 floats:
// [0..35]  sum mask*Re(s_i conj s_j)  (i<=j)   [RAW mask, not normalized]
// [36..63] sum mask*Im(s_i conj s_j) (i<j)
// [64..99] sum Re(s_i conj s_j)
// [100..127] sum Im(s_i conj s_j)
// [128] sum mask (raw)   [129] max |mask|
#define REC_STRIDE 132

__device__ inline float wredsum(float v) {
#pragma unroll
    for (int o = 32; o; o >>= 1) v += __shfl_down(v, o, 64);
    return v;
}
__device__ inline float wredmax(float v) {
#pragma unroll
    for (int o = 32; o; o >>= 1) v = fmaxf(v, __shfl_down(v, o, 64));
    return v;
}

// mask (n,t,f) -> maskT (n,f,t): 32x32 LDS tile transpose, both sides coalesced
__global__ __launch_bounds__(256) void mask_transpose_kernel(const float* __restrict__ mask,
                                                             float* __restrict__ maskT) {
    const int f0 = blockIdx.x * 32;
    const int t0 = blockIdx.y * 32;
    const int n = blockIdx.z;
    const int tx = threadIdx.x & 31, ty = threadIdx.x >> 5;  // 32 x 8
    __shared__ float tile[32][33];

#pragma unroll
    for (int k = 0; k < 4; k++) {
        int t = t0 + ty + 8 * k, f = f0 + tx;
        if (t < TT && f < FF) tile[ty + 8 * k][tx] = mask[((size_t)n * TT + t) * FF + f];
    }
    __syncthreads();
#pragma unroll
    for (int k = 0; k < 4; k++) {
        int f = f0 + ty + 8 * k, t = t0 + tx;
        if (f < FF && t < TT) maskT[((size_t)n * FF + f) * TT + t] = tile[tx][ty + 8 * k];
    }
}

// One block (4 waves) per (n,f); wave = kind, direct global loads (no LDS,
// no prefetch arrays -> stays at ~52 VGPR, zero scratch; learned r3-r6).
// kind 0: masked-real(+mask stats)  1: masked-imag
// kind 2: unmasked-real             3: unmasked-imag
// The 4 waves read the same x stream near-simultaneously -> one HBM fetch,
// L1/L2 serve the other three. Single writer per record field -> plain stores.
__global__ __launch_bounds__(256, 8) void cov_kernel(const float* __restrict__ maskT,
                                                     const float* __restrict__ xr,
                                                     const float* __restrict__ xi,
                                                     float* __restrict__ cov) {
    const int nf = blockIdx.x;
    const int n = nf / FF, f = nf % FF;
    const int wave = threadIdx.x >> 6, lane = threadIdx.x & 63;
    const bool isReal = (wave & 1) == 0;
    const bool isMasked = wave < 2;

    float acc[36] = {};
    float smask = 0.f, mmask = 0.f;

    const size_t cstride = (size_t)FF * TT;
    const float* xrb = xr + ((size_t)(n * CCH) * FF + f) * TT;
    const float* xib = xi + ((size_t)(n * CCH) * FF + f) * TT;
    const float* mt = maskT + ((size_t)n * FF + f) * TT;

#pragma unroll 4
    for (int it = 0; it < 16; ++it) {
        const int t = it * 64 + lane;
        if (t < TT) {                        // 1000 = 15*64 + 40
            float w = 1.0f;
            if (isMasked) {
                float mv = mt[t];
                w = mv;
                if (wave == 0) { smask += mv; mmask = fmaxf(mmask, fabsf(mv)); }
            }
            float ar[8], ai[8];
#pragma unroll
            for (int c = 0; c < 8; c++) {
                ar[c] = xrb[c * cstride + t];
                ai[c] = xib[c * cstride + t];
            }
            if (isReal) {
#pragma unroll
                for (int e = 0; e < 36; e++)
                    acc[e] += w * (ar[RI_[e]] * ar[RJ_[e]] + ai[RI_[e]] * ai[RJ_[e]]);
            } else {
#pragma unroll
                for (int e = 0; e < 28; e++)
                    acc[e] += w * (ai[QI_[e]] * ar[QJ_[e]] - ar[QI_[e]] * ai[QJ_[e]]);
            }
        }
    }

    float* rec = cov + (size_t)nf * REC_STRIDE;
    const int base = (wave == 0) ? 0 : (wave == 1) ? 36 : (wave == 2) ? 64 : 100;
    if (isReal) {
#pragma unroll
        for (int e = 0; e < 36; e++) {
            float v = wredsum(acc[e]);
            if (lane == 0) rec[base + e] = v;
        }
    } else {
#pragma unroll
        for (int e = 0; e < 28; e++) {
            float v = wredsum(acc[e]);
            if (lane == 0) rec[base + e] = v;
        }
    }
    if (wave == 0) {
        float st = wredsum(smask);
        float mtx = wredmax(mmask);
        if (lane == 0) { rec[128] = st; rec[129] = mtx; }
    }
}

// grid (dc=8, n=8); wave q handles channels 2q,2q+1; lane = d within chunk
__global__ __launch_bounds__(256) void attn_kernel(const float* __restrict__ cov,
                                                   const float* __restrict__ proj_w,
                                                   const float* __restrict__ proj_b,
                                                   const float* __restrict__ gvec_w,
                                                   float* __restrict__ gpart) {
    const int dc = blockIdx.x;
    const int n = blockIdx.y;
    const int tid = threadIdx.x;
    __shared__ float feat[8][FF];

    for (int f = tid; f < FF; f += 256) {
        const float* rec = cov + (size_t)(n * FF + f) * REC_STRIDE;
        float inv_mx = 1.0f / (rec[129] + EPSI);
        float sum_ms = rec[128] * inv_mx;
        float scale = inv_mx / (7.0f * fmaxf(sum_ms, EPSI));
#pragma unroll
        for (int i = 0; i < 8; i++) {
            float rr = 0.f, ri = 0.f;
#pragma unroll
            for (int j = 0; j < 8; j++) {
                if (j == i) continue;
                if (j > i) { rr += rec[PIDX(i, j)]; ri += rec[36 + QIDX(i, j)]; }
                else       { rr += rec[PIDX(j, i)]; ri -= rec[36 + QIDX(j, i)]; }
            }
            feat[i][f] = sqrtf(rr * rr + ri * ri) * scale;
        }
    }
    __syncthreads();

    const int wv = tid >> 6, lane = tid & 63;
    const int d = dc * 64 + lane;
    const int c0 = 2 * wv, c1 = c0 + 1;
    const float* pwd = proj_w + (size_t)d * FF;
    float a0 = proj_b[d], a1 = a0;
    for (int f = 0; f < FF; f++) {
        float w = pwd[f];
        a0 += w * feat[c0][f];
        a1 += w * feat[c1][f];
    }
    float gwd = gvec_w[d];
    float g0 = gwd * tanhf(a0);
    float g1 = gwd * tanhf(a1);
    g0 = wredsum(g0);
    g1 = wredsum(g1);
    if (!lane) {
        gpart[(n * 8 + dc) * 8 + c0] = g0;
        gpart[(n * 8 + dc) * 8 + c1] = g1;
    }
}

__global__ void attn2_kernel(const float* __restrict__ gpart, const float* __restrict__ gvec_b,
                             float* __restrict__ u) {
    const int n = blockIdx.x;
    const int lane = threadIdx.x;  // 64: dc*8 + c
    float v = gpart[n * 64 + lane];
    v += __shfl_xor(v, 8, 64);
    v += __shfl_xor(v, 16, 64);
    v += __shfl_xor(v, 32, 64);
    float g = v + gvec_b[0];
    float m = g;
    m = fmaxf(m, __shfl_xor(m, 1, 64));
    m = fmaxf(m, __shfl_xor(m, 2, 64));
    m = fmaxf(m, __shfl_xor(m, 4, 64));
    float e = expf(g - m);
    float s = e;
    s += __shfl_xor(s, 1, 64);
    s += __shfl_xor(s, 2, 64);
    s += __shfl_xor(s, 4, 64);
    if (lane < 8) u[n * 8 + lane] = e / s;
}

__global__ __launch_bounds__(64, 1) void solve_kernel(const float* __restrict__ cov,
                                                      const float* __restrict__ u,
                                                      float* __restrict__ wout) {
    const int idx = blockIdx.x * 64 + threadIdx.x;
    if (idx >= NB * FF) return;
    const int n = idx / FF;
    const float* rec = cov + (size_t)idx * REC_STRIDE;

    float raw = rec[128], mx = rec[129];
    float inv_mx = 1.0f / (mx + EPSI);
    float sum_ms = raw * inv_mx;
    float inv_s = 1.0f / fmaxf(sum_ms, EPSI);
    float inv_n = 1.0f / fmaxf((float)TT - sum_ms, EPSI);
    float ks = inv_mx * inv_s;   // Rs entry scale on raw masked sums

    float Ar[8][8], Ai[8][8], Br[8][8], Bi[8][8];  // A = Rn, B = Rs -> X
#pragma unroll
    for (int i = 0; i < 8; i++) {
#pragma unroll
        for (int j = i; j < 8; j++) {
            float mr = rec[PIDX(i, j)];
            float tr = rec[64 + PIDX(i, j)];
            float s_r = mr * ks;
            float n_r = (tr - mr * inv_mx) * inv_n;
            if (j == i) {
                Br[i][i] = s_r; Bi[i][i] = 0.f;
                Ar[i][i] = n_r + EPS5; Ai[i][i] = 0.f;
            } else {
                float mi = rec[36 + QIDX(i, j)];
                float ti = rec[100 + QIDX(i, j)];
                float s_i = mi * ks;
                float n_i = (ti - mi * inv_mx) * inv_n;
                Br[i][j] = s_r; Bi[i][j] = s_i;
                Br[j][i] = s_r; Bi[j][i] = -s_i;
                Ar[i][j] = n_r; Ai[i][j] = n_i;
                Ar[j][i] = n_r; Ai[j][i] = -n_i;
            }
        }
    }

    // forward elimination (no pivot: A is HPD + eps*I)
#pragma unroll
    for (int k = 0; k < 8; k++) {
        float dr = Ar[k][k], di = Ai[k][k];
        float iv = 1.0f / (dr * dr + di * di);
        float pir = dr * iv, pii = -di * iv;
#pragma unroll
        for (int r = k + 1; r < 8; r++) {
            float ar = Ar[r][k], ai = Ai[r][k];
            float fr = ar * pir - ai * pii;
            float fi = ar * pii + ai * pir;
#pragma unroll
            for (int j = k + 1; j < 8; j++) {
                Ar[r][j] -= fr * Ar[k][j] - fi * Ai[k][j];
                Ai[r][j] -= fr * Ai[k][j] + fi * Ar[k][j];
            }
#pragma unroll
            for (int j = 0; j < 8; j++) {
                Br[r][j] -= fr * Br[k][j] - fi * Bi[k][j];
                Bi[r][j] -= fr * Bi[k][j] + fi * Br[k][j];
            }
        }
    }
    // back substitution
#pragma unroll
    for (int k = 7; k >= 0; k--) {
        float dr = Ar[k][k], di = Ai[k][k];
        float iv = 1.0f / (dr * dr + di * di);
        float pir = dr * iv, pii = -di * iv;
#pragma unroll
        for (int j = 0; j < 8; j++) {
            float s_r = Br[k][j], s_i = Bi[k][j];
#pragma unroll
            for (int m = k + 1; m < 8; m++) {
                s_r -= Ar[k][m] * Br[m][j] - Ai[k][m] * Bi[m][j];
                s_i -= Ar[k][m] * Bi[m][j] + Ai[k][m] * Br[m][j];
            }
            Br[k][j] = s_r * pir - s_i * pii;
            Bi[k][j] = s_r * pii + s_i * pir;
        }
    }

    float trr = EPS5, tri = 0.f;
#pragma unroll
    for (int i = 0; i < 8; i++) { trr += Br[i][i]; tri += Bi[i][i]; }
    float tinv = 1.0f / (trr * trr + tri * tri);

    float* wo = wout + (size_t)idx * 16;
#pragma unroll
    for (int i = 0; i < 8; i++) {
        float nr = 0.f, ni = 0.f;
#pragma unroll
        for (int c = 0; c < 8; c++) {
            float uc = u[n * 8 + c];
            nr += Br[i][c] * uc;
            ni += Bi[i][c] * uc;
        }
        float wr = (nr * trr + ni * tri) * tinv;
        float wi = (ni * trr - nr * tri) * tinv;
        wo[i * 2] = wr;        // store conj(w): real
        wo[i * 2 + 1] = -wi;   // store conj(w): imag
    }
}

__global__ __launch_bounds__(256) void beam_kernel(const float* __restrict__ xr,
                                                   const float* __restrict__ xi,
                                                   const float* __restrict__ wc,
                                                   float* __restrict__ out) {
    const int n = blockIdx.z;
    const int f0 = blockIdx.y * 32;
    const int t0 = blockIdx.x * 64;
    const int tid = threadIdx.x;

    __shared__ float wlds[32][16];
    __shared__ float bldr[32][65];
    __shared__ float bldi[32][65];

    for (int s = tid; s < 32 * 16; s += 256) {
        int fl = s >> 4, rest = s & 15;
        int f = f0 + fl;
        wlds[fl][rest] = (f < FF) ? wc[(size_t)(n * FF + f) * 16 + rest] : 0.f;
    }
    __syncthreads();

    const int lane_t = tid & 63, row = tid >> 6;
    const int t = t0 + lane_t;
    const bool tok = t < TT;
    const size_t cstride = (size_t)FF * TT;

#pragma unroll
    for (int k = 0; k < 8; k++) {
        int fl = row + k * 4;
        int f = f0 + fl;
        float br = 0.f, bi = 0.f;
        if (f < FF && tok) {
            size_t base = ((size_t)(n * CCH) * FF + f) * TT + t;
#pragma unroll
            for (int c = 0; c < 8; c++) {
                float vr = xr[base + c * cstride];
                float vi = xi[base + c * cstride];
                float wr = wlds[fl][c * 2], wi_ = wlds[fl][c * 2 + 1];
                br += wr * vr - wi_ * vi;
                bi += wr * vi + wi_ * vr;
            }
        }
        bldr[fl][lane_t] = br;
        bldi[fl][lane_t] = bi;
    }
    __syncthreads();

    const int fc = tid & 31, trb = tid >> 5;
    const int f = f0 + fc;
    float2* outv = (float2*)out;
#pragma unroll
    for (int k = 0; k < 8; k++) {
        int tr = trb + k * 8;
        int t2 = t0 + tr;
        if (f < FF && t2 < TT) {
            float2 v = make_float2(bldr[fc][tr], bldi[fc][tr]);
            outv[(size_t)(n * TT + t2) * FF + f] = v;
        }
    }
}

extern "C" void kernel_launch(void* const* d_in, const int* in_sizes, int n_in,
                              void* d_out, int out_size, void* d_ws, size_t ws_size,
                              hipStream_t stream) {
    const float* mask = (const float*)d_in[0];
    const float* xr = (const float*)d_in[1];
    const float* xi = (const float*)d_in[2];
    const float* pw = (const float*)d_in[3];
    const float* pb = (const float*)d_in[4];
    const float* gw = (const float*)d_in[5];
    const float* gb = (const float*)d_in[6];
    float* out = (float*)d_out;
    float* ws = (float*)d_ws;

    float* maskT = ws;                                           // 8*257*1000
    float* cov = maskT + (size_t)NB * FF * TT;                   // 2056*132
    float* gpart = cov + (size_t)NB * FF * REC_STRIDE;           // 512
    float* u = gpart + 512;                                      // 64
    float* wv = u + 64;                                          // 2056*16

    hipLaunchKernelGGL(mask_transpose_kernel, dim3((FF + 31) / 32, (TT + 31) / 32, NB), dim3(256), 0, stream, mask, maskT);
    hipLaunchKernelGGL(cov_kernel, dim3(NB * FF), dim3(256), 0, stream, maskT, xr, xi, cov);
    hipLaunchKernelGGL(attn_kernel, dim3(8, NB), dim3(256), 0, stream, cov, pw, pb, gw, gpart);
    hipLaunchKernelGGL(attn2_kernel, dim3(NB), dim3(64), 0, stream, gpart, gb, u);
    hipLaunchKernelGGL(solve_kernel, dim3((NB * FF + 63) / 64), dim3(64), 0, stream, cov, u, wv);
    hipLaunchKernelGGL(beam_kernel, dim3((TT + 63) / 64, (FF + 31) / 32, NB), dim3(256), 0, stream, xr, xi, wv, out);
}

// Round 8
// 469.684 us; speedup vs baseline: 1.2479x; 1.2479x over previous
//
#include <hip/hip_runtime.h>
#include <hip/hip_bf16.h>
#include <cmath>

#define NB 8
#define CCH 8
#define FF 257
#define TT 1000
#define AD 512
#define EPSI 1.1920928955078125e-07f
#define EPS5 1e-05f
#define TCH 500

// pair indexing for Hermitian upper triangle (i<=j)
__host__ __device__ constexpr int PIDX(int i, int j) { return i * 8 - i * (i - 1) / 2 + (j - i); }        // 0..35
__host__ __device__ constexpr int QIDX(int i, int j) { return i * 7 - i * (i - 1) / 2 + (j - i - 1); }    // 0..27 (j>i)

// e -> (i,j) tables for the two triangles (compile-time folded in unrolled loops)
__device__ constexpr int RI_[36] = {0,0,0,0,0,0,0,0, 1,1,1,1,1,1,1, 2,2,2,2,2,2, 3,3,3,3,3, 4,4,4,4, 5,5,5, 6,6, 7};
__device__ constexpr int RJ_[36] = {0,1,2,3,4,5,6,7, 1,2,3,4,5,6,7, 2,3,4,5,6,7, 3,4,5,6,7, 4,5,6,7, 5,6,7, 6,7, 7};
__device__ constexpr int QI_[28] = {0,0,0,0,0,0,0, 1,1,1,1,1,1, 2,2,2,2,2, 3,3,3,3, 4,4,4, 5,5, 6};
__device__ constexpr int QJ_[28] = {1,2,3,4,5,6,7, 2,3,4,5,6,7, 3,4,5,6,7, 4,5,6,7, 5,6,7, 6,7, 7};

// final record layout per (n,f), stride 132 floats:
// [0..35]  sum mask*Re(s_i conj s_j)  (i<=j)   [RAW mask, not normalized]
// [36..63] sum mask*Im(s_i conj s_j) (i<j)
// [64..99] sum Re(s_i conj s_j)
// [100..127] sum Im(s_i conj s_j)
// [128] sum mask (raw)   [129] max |mask|
#define REC_STRIDE 132

__device__ inline float wredsum(float v) {
#pragma unroll
    for (int o = 32; o; o >>= 1) v += __shfl_down(v, o, 64);
    return v;
}
__device__ inline float wredmax(float v) {
#pragma unroll
    for (int o = 32; o; o >>= 1) v = fmaxf(v, __shfl_down(v, o, 64));
    return v;
}

// mask (n,t,f) -> maskT (n,f,t): 32x32 LDS tile transpose, both sides coalesced
__global__ __launch_bounds__(256) void mask_transpose_kernel(const float* __restrict__ mask,
                                                             float* __restrict__ maskT) {
    const int f0 = blockIdx.x * 32;
    const int t0 = blockIdx.y * 32;
    const int n = blockIdx.z;
    const int tx = threadIdx.x & 31, ty = threadIdx.x >> 5;  // 32 x 8
    __shared__ float tile[32][33];

#pragma unroll
    for (int k = 0; k < 4; k++) {
        int t = t0 + ty + 8 * k, f = f0 + tx;
        if (t < TT && f < FF) tile[ty + 8 * k][tx] = mask[((size_t)n * TT + t) * FF + f];
    }
    __syncthreads();
#pragma unroll
    for (int k = 0; k < 4; k++) {
        int f = f0 + ty + 8 * k, t = t0 + tx;
        if (f < FF && t < TT) maskT[((size_t)n * FF + f) * TT + t] = tile[tx][ty + 8 * k];
    }
}

// Block = 128 threads = 2 waves = the 2 t-chunks of one (n,f,kind).
// Per-wave code identical to the proven 52-VGPR round-5 loop (64-thread waves,
// <=36 reg accumulators, direct global loads, no LDS). kind on FASTEST grid
// dim so the 4 kinds' x reads are temporally adjacent (L2/L3 absorb 3 of 4).
// kind 0: masked-real(36)+mask stats  1: masked-imag(28)
// kind 2: unmasked-real(36)           3: unmasked-imag(28)
// Atomic finish: disjoint offsets per kind; 2 commutative contributors
// (chunks) per offset -> bitwise deterministic.
__global__ __launch_bounds__(128, 4) void cov_part_kernel(const float* __restrict__ maskT,
                                                          const float* __restrict__ xr,
                                                          const float* __restrict__ xi,
                                                          float* __restrict__ cov) {
    const int kind = blockIdx.x;         // 0..3
    const int f = blockIdx.y;            // 0..256
    const int n = blockIdx.z;            // 0..7
    const int ch = threadIdx.x >> 6;     // wave = chunk
    const int lane = threadIdx.x & 63;
    const int t0 = ch * TCH;
    const bool isReal = (kind & 1) == 0;
    const bool isMasked = kind < 2;

    float acc[36] = {};
    float smask = 0.f, mmask = 0.f;

    const size_t cstride = (size_t)FF * TT;
    const float* xrb = xr + ((size_t)(n * CCH) * FF + f) * TT;
    const float* xib = xi + ((size_t)(n * CCH) * FF + f) * TT;
    const float* mt = maskT + ((size_t)n * FF + f) * TT;

#pragma unroll
    for (int it = 0; it < 8; ++it) {
        const int tt = it * 64 + lane;
        if (tt < TCH) {                  // 500 = 7*64 + 52
            const int t = t0 + tt;
            float w = 1.0f;
            if (isMasked) {
                float mv = mt[t];
                w = mv;
                if (kind == 0) { smask += mv; mmask = fmaxf(mmask, fabsf(mv)); }
            }
            float ar[8], ai[8];
#pragma unroll
            for (int c = 0; c < 8; c++) {
                ar[c] = xrb[c * cstride + t];
                ai[c] = xib[c * cstride + t];
            }
            if (isReal) {
#pragma unroll
                for (int e = 0; e < 36; e++)
                    acc[e] += w * (ar[RI_[e]] * ar[RJ_[e]] + ai[RI_[e]] * ai[RJ_[e]]);
            } else {
#pragma unroll
                for (int e = 0; e < 28; e++)
                    acc[e] += w * (ai[QI_[e]] * ar[QJ_[e]] - ar[QI_[e]] * ai[QJ_[e]]);
            }
        }
    }

    float* rec = cov + ((size_t)n * FF + f) * REC_STRIDE;
    const int base = (kind == 0) ? 0 : (kind == 1) ? 36 : (kind == 2) ? 64 : 100;
    if (isReal) {
#pragma unroll
        for (int e = 0; e < 36; e++) {
            float v = wredsum(acc[e]);
            if (lane == 0) atomicAdd(&rec[base + e], v);
        }
    } else {
#pragma unroll
        for (int e = 0; e < 28; e++) {
            float v = wredsum(acc[e]);
            if (lane == 0) atomicAdd(&rec[base + e], v);
        }
    }
    if (kind == 0) {
        float st = wredsum(smask);
        float mtx = wredmax(mmask);
        if (lane == 0) {
            atomicAdd(&rec[128], st);
            atomicMax((int*)&rec[129], __float_as_int(mtx));  // valid: mask >= 0, init 0.0
        }
    }
}

// grid (dc=8, n=8); wave q handles channels 2q,2q+1; lane = d within chunk
__global__ __launch_bounds__(256) void attn_kernel(const float* __restrict__ cov,
                                                   const float* __restrict__ proj_w,
                                                   const float* __restrict__ proj_b,
                                                   const float* __restrict__ gvec_w,
                                                   float* __restrict__ gpart) {
    const int dc = blockIdx.x;
    const int n = blockIdx.y;
    const int tid = threadIdx.x;
    __shared__ float feat[8][FF];

    for (int f = tid; f < FF; f += 256) {
        const float* rec = cov + (size_t)(n * FF + f) * REC_STRIDE;
        float inv_mx = 1.0f / (rec[129] + EPSI);
        float sum_ms = rec[128] * inv_mx;
        float scale = inv_mx / (7.0f * fmaxf(sum_ms, EPSI));
#pragma unroll
        for (int i = 0; i < 8; i++) {
            float rr = 0.f, ri = 0.f;
#pragma unroll
            for (int j = 0; j < 8; j++) {
                if (j == i) continue;
                if (j > i) { rr += rec[PIDX(i, j)]; ri += rec[36 + QIDX(i, j)]; }
                else       { rr += rec[PIDX(j, i)]; ri -= rec[36 + QIDX(j, i)]; }
            }
            feat[i][f] = sqrtf(rr * rr + ri * ri) * scale;
        }
    }
    __syncthreads();

    const int wv = tid >> 6, lane = tid & 63;
    const int d = dc * 64 + lane;
    const int c0 = 2 * wv, c1 = c0 + 1;
    const float* pwd = proj_w + (size_t)d * FF;
    float a0 = proj_b[d], a1 = a0;
    for (int f = 0; f < FF; f++) {
        float w = pwd[f];
        a0 += w * feat[c0][f];
        a1 += w * feat[c1][f];
    }
    float gwd = gvec_w[d];
    float g0 = gwd * tanhf(a0);
    float g1 = gwd * tanhf(a1);
    g0 = wredsum(g0);
    g1 = wredsum(g1);
    if (!lane) {
        gpart[(n * 8 + dc) * 8 + c0] = g0;
        gpart[(n * 8 + dc) * 8 + c1] = g1;
    }
}

__global__ void attn2_kernel(const float* __restrict__ gpart, const float* __restrict__ gvec_b,
                             float* __restrict__ u) {
    const int n = blockIdx.x;
    const int lane = threadIdx.x;  // 64: dc*8 + c
    float v = gpart[n * 64 + lane];
    v += __shfl_xor(v, 8, 64);
    v += __shfl_xor(v, 16, 64);
    v += __shfl_xor(v, 32, 64);
    float g = v + gvec_b[0];
    float m = g;
    m = fmaxf(m, __shfl_xor(m, 1, 64));
    m = fmaxf(m, __shfl_xor(m, 2, 64));
    m = fmaxf(m, __shfl_xor(m, 4, 64));
    float e = expf(g - m);
    float s = e;
    s += __shfl_xor(s, 1, 64);
    s += __shfl_xor(s, 2, 64);
    s += __shfl_xor(s, 4, 64);
    if (lane < 8) u[n * 8 + lane] = e / s;
}

__global__ __launch_bounds__(64, 1) void solve_kernel(const float* __restrict__ cov,
                                                      const float* __restrict__ u,
                                                      float* __restrict__ wout) {
    const int idx = blockIdx.x * 64 + threadIdx.x;
    if (idx >= NB * FF) return;
    const int n = idx / FF;
    const float* rec = cov + (size_t)idx * REC_STRIDE;

    float raw = rec[128], mx = rec[129];
    float inv_mx = 1.0f / (mx + EPSI);
    float sum_ms = raw * inv_mx;
    float inv_s = 1.0f / fmaxf(sum_ms, EPSI);
    float inv_n = 1.0f / fmaxf((float)TT - sum_ms, EPSI);
    float ks = inv_mx * inv_s;   // Rs entry scale on raw masked sums

    float Ar[8][8], Ai[8][8], Br[8][8], Bi[8][8];  // A = Rn, B = Rs -> X
#pragma unroll
    for (int i = 0; i < 8; i++) {
#pragma unroll
        for (int j = i; j < 8; j++) {
            float mr = rec[PIDX(i, j)];
            float tr = rec[64 + PIDX(i, j)];
            float s_r = mr * ks;
            float n_r = (tr - mr * inv_mx) * inv_n;
            if (j == i) {
                Br[i][i] = s_r; Bi[i][i] = 0.f;
                Ar[i][i] = n_r + EPS5; Ai[i][i] = 0.f;
            } else {
                float mi = rec[36 + QIDX(i, j)];
                float ti = rec[100 + QIDX(i, j)];
                float s_i = mi * ks;
                float n_i = (ti - mi * inv_mx) * inv_n;
                Br[i][j] = s_r; Bi[i][j] = s_i;
                Br[j][i] = s_r; Bi[j][i] = -s_i;
                Ar[i][j] = n_r; Ai[i][j] = n_i;
                Ar[j][i] = n_r; Ai[j][i] = -n_i;
            }
        }
    }

    // forward elimination (no pivot: A is HPD + eps*I)
#pragma unroll
    for (int k = 0; k < 8; k++) {
        float dr = Ar[k][k], di = Ai[k][k];
        float iv = 1.0f / (dr * dr + di * di);
        float pir = dr * iv, pii = -di * iv;
#pragma unroll
        for (int r = k + 1; r < 8; r++) {
            float ar = Ar[r][k], ai = Ai[r][k];
            float fr = ar * pir - ai * pii;
            float fi = ar * pii + ai * pir;
#pragma unroll
            for (int j = k + 1; j < 8; j++) {
                Ar[r][j] -= fr * Ar[k][j] - fi * Ai[k][j];
                Ai[r][j] -= fr * Ai[k][j] + fi * Ar[k][j];
            }
#pragma unroll
            for (int j = 0; j < 8; j++) {
                Br[r][j] -= fr * Br[k][j] - fi * Bi[k][j];
                Bi[r][j] -= fr * Bi[k][j] + fi * Br[k][j];
            }
        }
    }
    // back substitution
#pragma unroll
    for (int k = 7; k >= 0; k--) {
        float dr = Ar[k][k], di = Ai[k][k];
        float iv = 1.0f / (dr * dr + di * di);
        float pir = dr * iv, pii = -di * iv;
#pragma unroll
        for (int j = 0; j < 8; j++) {
            float s_r = Br[k][j], s_i = Bi[k][j];
#pragma unroll
            for (int m = k + 1; m < 8; m++) {
                s_r -= Ar[k][m] * Br[m][j] - Ai[k][m] * Bi[m][j];
                s_i -= Ar[k][m] * Bi[m][j] + Ai[k][m] * Br[m][j];
            }
            Br[k][j] = s_r * pir - s_i * pii;
            Bi[k][j] = s_r * pii + s_i * pir;
        }
    }

    float trr = EPS5, tri = 0.f;
#pragma unroll
    for (int i = 0; i < 8; i++) { trr += Br[i][i]; tri += Bi[i][i]; }
    float tinv = 1.0f / (trr * trr + tri * tri);

    float* wo = wout + (size_t)idx * 16;
#pragma unroll
    for (int i = 0; i < 8; i++) {
        float nr = 0.f, ni = 0.f;
#pragma unroll
        for (int c = 0; c < 8; c++) {
            float uc = u[n * 8 + c];
            nr += Br[i][c] * uc;
            ni += Bi[i][c] * uc;
        }
        float wr = (nr * trr + ni * tri) * tinv;
        float wi = (ni * trr - nr * tri) * tinv;
        wo[i * 2] = wr;        // store conj(w): real
        wo[i * 2 + 1] = -wi;   // store conj(w): imag
    }
}

__global__ __launch_bounds__(256) void beam_kernel(const float* __restrict__ xr,
                                                   const float* __restrict__ xi,
                                                   const float* __restrict__ wc,
                                                   float* __restrict__ out) {
    const int n = blockIdx.z;
    const int f0 = blockIdx.y * 32;
    const int t0 = blockIdx.x * 64;
    const int tid = threadIdx.x;

    __shared__ float wlds[32][16];
    __shared__ float bldr[32][65];
    __shared__ float bldi[32][65];

    for (int s = tid; s < 32 * 16; s += 256) {
        int fl = s >> 4, rest = s & 15;
        int f = f0 + fl;
        wlds[fl][rest] = (f < FF) ? wc[(size_t)(n * FF + f) * 16 + rest] : 0.f;
    }
    __syncthreads();

    const int lane_t = tid & 63, row = tid >> 6;
    const int t = t0 + lane_t;
    const bool tok = t < TT;
    const size_t cstride = (size_t)FF * TT;

#pragma unroll
    for (int k = 0; k < 8; k++) {
        int fl = row + k * 4;
        int f = f0 + fl;
        float br = 0.f, bi = 0.f;
        if (f < FF && tok) {
            size_t base = ((size_t)(n * CCH) * FF + f) * TT + t;
#pragma unroll
            for (int c = 0; c < 8; c++) {
                float vr = xr[base + c * cstride];
                float vi = xi[base + c * cstride];
                float wr = wlds[fl][c * 2], wi_ = wlds[fl][c * 2 + 1];
                br += wr * vr - wi_ * vi;
                bi += wr * vi + wi_ * vr;
            }
        }
        bldr[fl][lane_t] = br;
        bldi[fl][lane_t] = bi;
    }
    __syncthreads();

    const int fc = tid & 31, trb = tid >> 5;
    const int f = f0 + fc;
    float2* outv = (float2*)out;
#pragma unroll
    for (int k = 0; k < 8; k++) {
        int tr = trb + k * 8;
        int t2 = t0 + tr;
        if (f < FF && t2 < TT) {
            float2 v = make_float2(bldr[fc][tr], bldi[fc][tr]);
            outv[(size_t)(n * TT + t2) * FF + f] = v;
        }
    }
}

extern "C" void kernel_launch(void* const* d_in, const int* in_sizes, int n_in,
                              void* d_out, int out_size, void* d_ws, size_t ws_size,
                              hipStream_t stream) {
    const float* mask = (const float*)d_in[0];
    const float* xr = (const float*)d_in[1];
    const float* xi = (const float*)d_in[2];
    const float* pw = (const float*)d_in[3];
    const float* pb = (const float*)d_in[4];
    const float* gw = (const float*)d_in[5];
    const float* gb = (const float*)d_in[6];
    float* out = (float*)d_out;
    float* ws = (float*)d_ws;

    float* maskT = ws;                                           // 8*257*1000
    float* cov = maskT + (size_t)NB * FF * TT;                   // 2056*132
    float* gpart = cov + (size_t)NB * FF * REC_STRIDE;           // 512
    float* u = gpart + 512;                                      // 64
    float* wv = u + 64;                                          // 2056*16

    // atomics accumulate into cov -> zero it every launch (graph-capture-safe)
    hipMemsetAsync(cov, 0, (size_t)NB * FF * REC_STRIDE * sizeof(float), stream);

    hipLaunchKernelGGL(mask_transpose_kernel, dim3((FF + 31) / 32, (TT + 31) / 32, NB), dim3(256), 0, stream, mask, maskT);
    hipLaunchKernelGGL(cov_part_kernel, dim3(4, FF, NB), dim3(128), 0, stream, maskT, xr, xi, cov);
    hipLaunchKernelGGL(attn_kernel, dim3(8, NB), dim3(256), 0, stream, cov, pw, pb, gw, gpart);
    hipLaunchKernelGGL(attn2_kernel, dim3(NB), dim3(64), 0, stream, gpart, gb, u);
    hipLaunchKernelGGL(solve_kernel, dim3((NB * FF + 63) / 64), dim3(64), 0, stream, cov, u, wv);
    hipLaunchKernelGGL(beam_kernel, dim3((TT + 63) / 64, (FF + 31) / 32, NB), dim3(256), 0, stream, xr, xi, wv, out);
}

// Round 9
// 314.066 us; speedup vs baseline: 1.8663x; 1.4955x over previous
//
#include <hip/hip_runtime.h>
#include <hip/hip_bf16.h>
#include <cmath>

#define NB 8
#define CCH 8
#define FF 257
#define TT 1000
#define AD 512
#define EPSI 1.1920928955078125e-07f
#define EPS5 1e-05f
#define NCHUNK 2
#define TCH 500

// pair indexing for Hermitian upper triangle (i<=j)
__host__ __device__ constexpr int PIDX(int i, int j) { return i * 8 - i * (i - 1) / 2 + (j - i); }        // 0..35
__host__ __device__ constexpr int QIDX(int i, int j) { return i * 7 - i * (i - 1) / 2 + (j - i - 1); }    // 0..27 (j>i)

// e -> (i,j) tables for the two triangles (compile-time folded in unrolled loops)
__device__ constexpr int RI_[36] = {0,0,0,0,0,0,0,0, 1,1,1,1,1,1,1, 2,2,2,2,2,2, 3,3,3,3,3, 4,4,4,4, 5,5,5, 6,6, 7};
__device__ constexpr int RJ_[36] = {0,1,2,3,4,5,6,7, 1,2,3,4,5,6,7, 2,3,4,5,6,7, 3,4,5,6,7, 4,5,6,7, 5,6,7, 6,7, 7};
__device__ constexpr int QI_[28] = {0,0,0,0,0,0,0, 1,1,1,1,1,1, 2,2,2,2,2, 3,3,3,3, 4,4,4, 5,5, 6};
__device__ constexpr int QJ_[28] = {1,2,3,4,5,6,7, 2,3,4,5,6,7, 3,4,5,6,7, 4,5,6,7, 5,6,7, 6,7, 7};

// final record layout per (n,f), stride 132 floats:
// [0..35]  sum mask*Re(s_i conj s_j)  (i<=j)   [RAW mask, not normalized]
// [36..63] sum mask*Im(s_i conj s_j) (i<j)
// [64..99] sum Re(s_i conj s_j)
// [100..127] sum Im(s_i conj s_j)
// [128] sum mask (raw)   [129] max |mask|
#define REC_STRIDE 132

__device__ inline float wredsum(float v) {
#pragma unroll
    for (int o = 32; o; o >>= 1) v += __shfl_down(v, o, 64);
    return v;
}
__device__ inline float wredmax(float v) {
#pragma unroll
    for (int o = 32; o; o >>= 1) v = fmaxf(v, __shfl_down(v, o, 64));
    return v;
}

// mask (n,t,f) -> maskT (n,f,t): 32x32 LDS tile transpose, both sides coalesced
__global__ __launch_bounds__(256) void mask_transpose_kernel(const float* __restrict__ mask,
                                                             float* __restrict__ maskT) {
    const int f0 = blockIdx.x * 32;
    const int t0 = blockIdx.y * 32;
    const int n = blockIdx.z;
    const int tx = threadIdx.x & 31, ty = threadIdx.x >> 5;  // 32 x 8
    __shared__ float tile[32][33];

#pragma unroll
    for (int k = 0; k < 4; k++) {
        int t = t0 + ty + 8 * k, f = f0 + tx;
        if (t < TT && f < FF) tile[ty + 8 * k][tx] = mask[((size_t)n * TT + t) * FF + f];
    }
    __syncthreads();
#pragma unroll
    for (int k = 0; k < 4; k++) {
        int f = f0 + ty + 8 * k, t = t0 + tx;
        if (f < FF && t < TT) maskT[((size_t)n * FF + f) * TT + t] = tile[tx][ty + 8 * k];
    }
}

// One 256-thread block per (n,f,chunk); wave = kind. NO second launch_bounds
// arg (r1/r6/r7/r8 all spilled when it forced a VGPR tier; r2's plain
// __launch_bounds__(256) held 65 accs/thread at VGPR 60 with zero scratch).
// The 4 kind-waves stream the same x slice simultaneously -> one L1 fetch;
// chunks are disjoint in t -> x fetched from HBM exactly once chip-wide.
// kind 0: masked-real(36)+mask stats  1: masked-imag(28)
// kind 2: unmasked-real(36)           3: unmasked-imag(28)
// Atomic finish: disjoint offsets per kind; exactly 2 commutative
// contributors (chunks) per offset -> bitwise deterministic.
__global__ __launch_bounds__(256) void cov_kernel(const float* __restrict__ maskT,
                                                  const float* __restrict__ xr,
                                                  const float* __restrict__ xi,
                                                  float* __restrict__ cov) {
    const int f = blockIdx.x;            // 0..256
    const int n = blockIdx.y;            // 0..7
    const int ch = blockIdx.z;           // 0..1
    const int kind = threadIdx.x >> 6;   // wave = kind
    const int lane = threadIdx.x & 63;
    const int t0 = ch * TCH;
    const bool isReal = (kind & 1) == 0;
    const bool isMasked = kind < 2;

    float acc[36] = {};
    float smask = 0.f, mmask = 0.f;

    const size_t cstride = (size_t)FF * TT;
    const float* xrb = xr + ((size_t)(n * CCH) * FF + f) * TT;
    const float* xib = xi + ((size_t)(n * CCH) * FF + f) * TT;
    const float* mt = maskT + ((size_t)n * FF + f) * TT;

#pragma unroll
    for (int it = 0; it < 8; ++it) {
        const int tt = it * 64 + lane;
        if (tt < TCH) {                  // 500 = 7*64 + 52
            const int t = t0 + tt;
            float w = 1.0f;
            if (isMasked) {
                float mv = mt[t];
                w = mv;
                if (kind == 0) { smask += mv; mmask = fmaxf(mmask, fabsf(mv)); }
            }
            float ar[8], ai[8];
#pragma unroll
            for (int c = 0; c < 8; c++) {
                ar[c] = xrb[c * cstride + t];
                ai[c] = xib[c * cstride + t];
            }
            if (isReal) {
#pragma unroll
                for (int e = 0; e < 36; e++)
                    acc[e] += w * (ar[RI_[e]] * ar[RJ_[e]] + ai[RI_[e]] * ai[RJ_[e]]);
            } else {
#pragma unroll
                for (int e = 0; e < 28; e++)
                    acc[e] += w * (ai[QI_[e]] * ar[QJ_[e]] - ar[QI_[e]] * ai[QJ_[e]]);
            }
        }
    }

    float* rec = cov + ((size_t)n * FF + f) * REC_STRIDE;
    const int base = (kind == 0) ? 0 : (kind == 1) ? 36 : (kind == 2) ? 64 : 100;
    if (isReal) {
#pragma unroll
        for (int e = 0; e < 36; e++) {
            float v = wredsum(acc[e]);
            if (lane == 0) atomicAdd(&rec[base + e], v);
        }
    } else {
#pragma unroll
        for (int e = 0; e < 28; e++) {
            float v = wredsum(acc[e]);
            if (lane == 0) atomicAdd(&rec[base + e], v);
        }
    }
    if (kind == 0) {
        float st = wredsum(smask);
        float mtx = wredmax(mmask);
        if (lane == 0) {
            atomicAdd(&rec[128], st);
            atomicMax((int*)&rec[129], __float_as_int(mtx));  // valid: mask >= 0, init 0.0
        }
    }
}

// grid (dc=8, n=8); wave q handles channels 2q,2q+1; lane = d within chunk
__global__ __launch_bounds__(256) void attn_kernel(const float* __restrict__ cov,
                                                   const float* __restrict__ proj_w,
                                                   const float* __restrict__ proj_b,
                                                   const float* __restrict__ gvec_w,
                                                   float* __restrict__ gpart) {
    const int dc = blockIdx.x;
    const int n = blockIdx.y;
    const int tid = threadIdx.x;
    __shared__ float feat[8][FF];

    for (int f = tid; f < FF; f += 256) {
        const float* rec = cov + (size_t)(n * FF + f) * REC_STRIDE;
        float inv_mx = 1.0f / (rec[129] + EPSI);
        float sum_ms = rec[128] * inv_mx;
        float scale = inv_mx / (7.0f * fmaxf(sum_ms, EPSI));
#pragma unroll
        for (int i = 0; i < 8; i++) {
            float rr = 0.f, ri = 0.f;
#pragma unroll
            for (int j = 0; j < 8; j++) {
                if (j == i) continue;
                if (j > i) { rr += rec[PIDX(i, j)]; ri += rec[36 + QIDX(i, j)]; }
                else       { rr += rec[PIDX(j, i)]; ri -= rec[36 + QIDX(j, i)]; }
            }
            feat[i][f] = sqrtf(rr * rr + ri * ri) * scale;
        }
    }
    __syncthreads();

    const int wv = tid >> 6, lane = tid & 63;
    const int d = dc * 64 + lane;
    const int c0 = 2 * wv, c1 = c0 + 1;
    const float* pwd = proj_w + (size_t)d * FF;
    float a0 = proj_b[d], a1 = a0;
    for (int f = 0; f < FF; f++) {
        float w = pwd[f];
        a0 += w * feat[c0][f];
        a1 += w * feat[c1][f];
    }
    float gwd = gvec_w[d];
    float g0 = gwd * tanhf(a0);
    float g1 = gwd * tanhf(a1);
    g0 = wredsum(g0);
    g1 = wredsum(g1);
    if (!lane) {
        gpart[(n * 8 + dc) * 8 + c0] = g0;
        gpart[(n * 8 + dc) * 8 + c1] = g1;
    }
}

__global__ void attn2_kernel(const float* __restrict__ gpart, const float* __restrict__ gvec_b,
                             float* __restrict__ u) {
    const int n = blockIdx.x;
    const int lane = threadIdx.x;  // 64: dc*8 + c
    float v = gpart[n * 64 + lane];
    v += __shfl_xor(v, 8, 64);
    v += __shfl_xor(v, 16, 64);
    v += __shfl_xor(v, 32, 64);
    float g = v + gvec_b[0];
    float m = g;
    m = fmaxf(m, __shfl_xor(m, 1, 64));
    m = fmaxf(m, __shfl_xor(m, 2, 64));
    m = fmaxf(m, __shfl_xor(m, 4, 64));
    float e = expf(g - m);
    float s = e;
    s += __shfl_xor(s, 1, 64);
    s += __shfl_xor(s, 2, 64);
    s += __shfl_xor(s, 4, 64);
    if (lane < 8) u[n * 8 + lane] = e / s;
}

__global__ __launch_bounds__(64) void solve_kernel(const float* __restrict__ cov,
                                                   const float* __restrict__ u,
                                                   float* __restrict__ wout) {
    const int idx = blockIdx.x * 64 + threadIdx.x;
    if (idx >= NB * FF) return;
    const int n = idx / FF;
    const float* rec = cov + (size_t)idx * REC_STRIDE;

    float raw = rec[128], mx = rec[129];
    float inv_mx = 1.0f / (mx + EPSI);
    float sum_ms = raw * inv_mx;
    float inv_s = 1.0f / fmaxf(sum_ms, EPSI);
    float inv_n = 1.0f / fmaxf((float)TT - sum_ms, EPSI);
    float ks = inv_mx * inv_s;   // Rs entry scale on raw masked sums

    float Ar[8][8], Ai[8][8], Br[8][8], Bi[8][8];  // A = Rn, B = Rs -> X
#pragma unroll
    for (int i = 0; i < 8; i++) {
#pragma unroll
        for (int j = i; j < 8; j++) {
            float mr = rec[PIDX(i, j)];
            float tr = rec[64 + PIDX(i, j)];
            float s_r = mr * ks;
            float n_r = (tr - mr * inv_mx) * inv_n;
            if (j == i) {
                Br[i][i] = s_r; Bi[i][i] = 0.f;
                Ar[i][i] = n_r + EPS5; Ai[i][i] = 0.f;
            } else {
                float mi = rec[36 + QIDX(i, j)];
                float ti = rec[100 + QIDX(i, j)];
                float s_i = mi * ks;
                float n_i = (ti - mi * inv_mx) * inv_n;
                Br[i][j] = s_r; Bi[i][j] = s_i;
                Br[j][i] = s_r; Bi[j][i] = -s_i;
                Ar[i][j] = n_r; Ai[i][j] = n_i;
                Ar[j][i] = n_r; Ai[j][i] = -n_i;
            }
        }
    }

    // forward elimination (no pivot: A is HPD + eps*I)
#pragma unroll
    for (int k = 0; k < 8; k++) {
        float dr = Ar[k][k], di = Ai[k][k];
        float iv = 1.0f / (dr * dr + di * di);
        float pir = dr * iv, pii = -di * iv;
#pragma unroll
        for (int r = k + 1; r < 8; r++) {
            float ar = Ar[r][k], ai = Ai[r][k];
            float fr = ar * pir - ai * pii;
            float fi = ar * pii + ai * pir;
#pragma unroll
            for (int j = k + 1; j < 8; j++) {
                Ar[r][j] -= fr * Ar[k][j] - fi * Ai[k][j];
                Ai[r][j] -= fr * Ai[k][j] + fi * Ar[k][j];
            }
#pragma unroll
            for (int j = 0; j < 8; j++) {
                Br[r][j] -= fr * Br[k][j] - fi * Bi[k][j];
                Bi[r][j] -= fr * Bi[k][j] + fi * Br[k][j];
            }
        }
    }
    // back substitution
#pragma unroll
    for (int k = 7; k >= 0; k--) {
        float dr = Ar[k][k], di = Ai[k][k];
        float iv = 1.0f / (dr * dr + di * di);
        float pir = dr * iv, pii = -di * iv;
#pragma unroll
        for (int j = 0; j < 8; j++) {
            float s_r = Br[k][j], s_i = Bi[k][j];
#pragma unroll
            for (int m = k + 1; m < 8; m++) {
                s_r -= Ar[k][m] * Br[m][j] - Ai[k][m] * Bi[m][j];
                s_i -= Ar[k][m] * Bi[m][j] + Ai[k][m] * Br[m][j];
            }
            Br[k][j] = s_r * pir - s_i * pii;
            Bi[k][j] = s_r * pii + s_i * pir;
        }
    }

    float trr = EPS5, tri = 0.f;
#pragma unroll
    for (int i = 0; i < 8; i++) { trr += Br[i][i]; tri += Bi[i][i]; }
    float tinv = 1.0f / (trr * trr + tri * tri);

    float* wo = wout + (size_t)idx * 16;
#pragma unroll
    for (int i = 0; i < 8; i++) {
        float nr = 0.f, ni = 0.f;
#pragma unroll
        for (int c = 0; c < 8; c++) {
            float uc = u[n * 8 + c];
            nr += Br[i][c] * uc;
            ni += Bi[i][c] * uc;
        }
        float wr = (nr * trr + ni * tri) * tinv;
        float wi = (ni * trr - nr * tri) * tinv;
        wo[i * 2] = wr;        // store conj(w): real
        wo[i * 2 + 1] = -wi;   // store conj(w): imag
    }
}

__global__ __launch_bounds__(256) void beam_kernel(const float* __restrict__ xr,
                                                   const float* __restrict__ xi,
                                                   const float* __restrict__ wc,
                                                   float* __restrict__ out) {
    const int n = blockIdx.z;
    const int f0 = blockIdx.y * 32;
    const int t0 = blockIdx.x * 64;
    const int tid = threadIdx.x;

    __shared__ float wlds[32][16];
    __shared__ float bldr[32][65];
    __shared__ float bldi[32][65];

    for (int s = tid; s < 32 * 16; s += 256) {
        int fl = s >> 4, rest = s & 15;
        int f = f0 + fl;
        wlds[fl][rest] = (f < FF) ? wc[(size_t)(n * FF + f) * 16 + rest] : 0.f;
    }
    __syncthreads();

    const int lane_t = tid & 63, row = tid >> 6;
    const int t = t0 + lane_t;
    const bool tok = t < TT;
    const size_t cstride = (size_t)FF * TT;

#pragma unroll
    for (int k = 0; k < 8; k++) {
        int fl = row + k * 4;
        int f = f0 + fl;
        float br = 0.f, bi = 0.f;
        if (f < FF && tok) {
            size_t base = ((size_t)(n * CCH) * FF + f) * TT + t;
#pragma unroll
            for (int c = 0; c < 8; c++) {
                float vr = xr[base + c * cstride];
                float vi = xi[base + c * cstride];
                float wr = wlds[fl][c * 2], wi_ = wlds[fl][c * 2 + 1];
                br += wr * vr - wi_ * vi;
                bi += wr * vi + wi_ * vr;
            }
        }
        bldr[fl][lane_t] = br;
        bldi[fl][lane_t] = bi;
    }
    __syncthreads();

    const int fc = tid & 31, trb = tid >> 5;
    const int f = f0 + fc;
    float2* outv = (float2*)out;
#pragma unroll
    for (int k = 0; k < 8; k++) {
        int tr = trb + k * 8;
        int t2 = t0 + tr;
        if (f < FF && t2 < TT) {
            float2 v = make_float2(bldr[fc][tr], bldi[fc][tr]);
            outv[(size_t)(n * TT + t2) * FF + f] = v;
        }
    }
}

extern "C" void kernel_launch(void* const* d_in, const int* in_sizes, int n_in,
                              void* d_out, int out_size, void* d_ws, size_t ws_size,
                              hipStream_t stream) {
    const float* mask = (const float*)d_in[0];
    const float* xr = (const float*)d_in[1];
    const float* xi = (const float*)d_in[2];
    const float* pw = (const float*)d_in[3];
    const float* pb = (const float*)d_in[4];
    const float* gw = (const float*)d_in[5];
    const float* gb = (const float*)d_in[6];
    float* out = (float*)d_out;
    float* ws = (float*)d_ws;

    float* maskT = ws;                                           // 8*257*1000
    float* cov = maskT + (size_t)NB * FF * TT;                   // 2056*132
    float* gpart = cov + (size_t)NB * FF * REC_STRIDE;           // 512
    float* u = gpart + 512;                                      // 64
    float* wv = u + 64;                                          // 2056*16

    // atomics accumulate into cov -> zero it every launch (graph-capture-safe)
    hipMemsetAsync(cov, 0, (size_t)NB * FF * REC_STRIDE * sizeof(float), stream);

    hipLaunchKernelGGL(mask_transpose_kernel, dim3((FF + 31) / 32, (TT + 31) / 32, NB), dim3(256), 0, stream, mask, maskT);
    hipLaunchKernelGGL(cov_kernel, dim3(FF, NB, NCHUNK), dim3(256), 0, stream, maskT, xr, xi, cov);
    hipLaunchKernelGGL(attn_kernel, dim3(8, NB), dim3(256), 0, stream, cov, pw, pb, gw, gpart);
    hipLaunchKernelGGL(attn2_kernel, dim3(NB), dim3(64), 0, stream, gpart, gb, u);
    hipLaunchKernelGGL(solve_kernel, dim3((NB * FF + 63) / 64), dim3(64), 0, stream, cov, u, wv);
    hipLaunchKernelGGL(beam_kernel, dim3((TT + 63) / 64, (FF + 31) / 32, NB), dim3(256), 0, stream, xr, xi, wv, out);
}

// Round 10
// 220.583 us; speedup vs baseline: 2.6572x; 1.4238x over previous
//
#include <hip/hip_runtime.h>
#include <hip/hip_bf16.h>
#include <cmath>

#define NB 8
#define CCH 8
#define FF 257
#define TT 1000
#define AD 512
#define EPSI 1.1920928955078125e-07f
#define EPS5 1e-05f
#define TQ 250   // t per wave (4 waves cover 1000)

// pair indexing for Hermitian upper triangle (i<=j)
__host__ __device__ constexpr int PIDX(int i, int j) { return i * 8 - i * (i - 1) / 2 + (j - i); }        // 0..35
__host__ __device__ constexpr int QIDX(int i, int j) { return i * 7 - i * (i - 1) / 2 + (j - i - 1); }    // 0..27 (j>i)

// e -> (i,j) tables for the two triangles (compile-time folded in unrolled loops)
__device__ constexpr int RI_[36] = {0,0,0,0,0,0,0,0, 1,1,1,1,1,1,1, 2,2,2,2,2,2, 3,3,3,3,3, 4,4,4,4, 5,5,5, 6,6, 7};
__device__ constexpr int RJ_[36] = {0,1,2,3,4,5,6,7, 1,2,3,4,5,6,7, 2,3,4,5,6,7, 3,4,5,6,7, 4,5,6,7, 5,6,7, 6,7, 7};
__device__ constexpr int QI_[28] = {0,0,0,0,0,0,0, 1,1,1,1,1,1, 2,2,2,2,2, 3,3,3,3, 4,4,4, 5,5, 6};
__device__ constexpr int QJ_[28] = {1,2,3,4,5,6,7, 2,3,4,5,6,7, 3,4,5,6,7, 4,5,6,7, 5,6,7, 6,7, 7};

// final record layout per (n,f), stride 132 floats:
// [0..35]  sum mask*Re(s_i conj s_j)  (i<=j)   [RAW mask, not normalized]
// [36..63] sum mask*Im(s_i conj s_j) (i<j)
// [64..99] sum Re(s_i conj s_j)
// [100..127] sum Im(s_i conj s_j)
// [128] sum mask (raw)   [129] max |mask|
#define REC_STRIDE 132

__device__ inline float wredsum(float v) {
#pragma unroll
    for (int o = 32; o; o >>= 1) v += __shfl_down(v, o, 64);
    return v;
}
__device__ inline float wredmax(float v) {
#pragma unroll
    for (int o = 32; o; o >>= 1) v = fmaxf(v, __shfl_down(v, o, 64));
    return v;
}

// mask (n,t,f) -> maskT (n,f,t): 32x32 LDS tile transpose, both sides coalesced
__global__ __launch_bounds__(256) void mask_transpose_kernel(const float* __restrict__ mask,
                                                             float* __restrict__ maskT) {
    const int f0 = blockIdx.x * 32;
    const int t0 = blockIdx.y * 32;
    const int n = blockIdx.z;
    const int tx = threadIdx.x & 31, ty = threadIdx.x >> 5;  // 32 x 8
    __shared__ float tile[32][33];

#pragma unroll
    for (int k = 0; k < 4; k++) {
        int t = t0 + ty + 8 * k, f = f0 + tx;
        if (t < TT && f < FF) tile[ty + 8 * k][tx] = mask[((size_t)n * TT + t) * FF + f];
    }
    __syncthreads();
#pragma unroll
    for (int k = 0; k < 4; k++) {
        int f = f0 + ty + 8 * k, t = t0 + tx;
        if (f < FF && t < TT) maskT[((size_t)n * FF + f) * TT + t] = tile[tx][ty + 8 * k];
    }
}

// Block = 256 threads = 4 waves; one block per (kind, f, n).
// kind comes from blockIdx.x (WAVE-UNIFORM -> single code path, ~52-60 VGPR;
// r9 proved wave-indexed kind unions paths to 144 VGPR and kills occupancy).
// Wave w covers t in [w*250, w*250+250). Plain __launch_bounds__(256) -- a
// min-waves 2nd arg forced spill tiers in r1/r6/r7/r8.
// kind 0: masked-real(36)+mask stats  1: masked-imag(28)
// kind 2: unmasked-real(36)           3: unmasked-imag(28)
// All contributors to a field are in ONE block -> LDS cross-wave reduce +
// plain store (no atomics, no memset, deterministic).
__global__ __launch_bounds__(256) void cov_kernel(const float* __restrict__ maskT,
                                                  const float* __restrict__ xr,
                                                  const float* __restrict__ xi,
                                                  float* __restrict__ cov) {
    const int kind = blockIdx.x;         // 0..3, wave-uniform
    const int f = blockIdx.y;            // 0..256
    const int n = blockIdx.z;            // 0..7
    const int wave = threadIdx.x >> 6;   // t-quarter
    const int lane = threadIdx.x & 63;
    const int t0 = wave * TQ;
    const bool isReal = (kind & 1) == 0;
    const bool isMasked = kind < 2;

    __shared__ float red[4][38];

    float acc[36] = {};
    float smask = 0.f, mmask = 0.f;

    const size_t cstride = (size_t)FF * TT;
    const float* xrb = xr + ((size_t)(n * CCH) * FF + f) * TT;
    const float* xib = xi + ((size_t)(n * CCH) * FF + f) * TT;
    const float* mt = maskT + ((size_t)n * FF + f) * TT;

#pragma unroll
    for (int it = 0; it < 4; ++it) {
        const int tt = it * 64 + lane;
        if (tt < TQ) {                   // 250 = 3*64 + 58
            const int t = t0 + tt;
            float w = 1.0f;
            if (isMasked) {
                float mv = mt[t];
                w = mv;
                if (kind == 0) { smask += mv; mmask = fmaxf(mmask, fabsf(mv)); }
            }
            float ar[8], ai[8];
#pragma unroll
            for (int c = 0; c < 8; c++) {
                ar[c] = xrb[c * cstride + t];
                ai[c] = xib[c * cstride + t];
            }
            if (isReal) {
#pragma unroll
                for (int e = 0; e < 36; e++)
                    acc[e] += w * (ar[RI_[e]] * ar[RJ_[e]] + ai[RI_[e]] * ai[RJ_[e]]);
            } else {
#pragma unroll
                for (int e = 0; e < 28; e++)
                    acc[e] += w * (ai[QI_[e]] * ar[QJ_[e]] - ar[QI_[e]] * ai[QJ_[e]]);
            }
        }
    }

    const int ne = isReal ? 36 : 28;
#pragma unroll
    for (int e = 0; e < 36; e++) {
        if (e < ne) {
            float v = wredsum(acc[e]);
            if (lane == 0) red[wave][e] = v;
        }
    }
    if (kind == 0) {
        float st = wredsum(smask);
        float mtx = wredmax(mmask);
        if (lane == 0) { red[wave][36] = st; red[wave][37] = mtx; }
    }
    __syncthreads();

    float* rec = cov + ((size_t)n * FF + f) * REC_STRIDE;
    const int base = (kind == 0) ? 0 : (kind == 1) ? 36 : (kind == 2) ? 64 : 100;
    if (threadIdx.x < (unsigned)ne)
        rec[base + threadIdx.x] = red[0][threadIdx.x] + red[1][threadIdx.x] +
                                  red[2][threadIdx.x] + red[3][threadIdx.x];
    if (kind == 0 && threadIdx.x == 64) {
        rec[128] = red[0][36] + red[1][36] + red[2][36] + red[3][36];
        rec[129] = fmaxf(fmaxf(red[0][37], red[1][37]), fmaxf(red[2][37], red[3][37]));
    }
}

// grid (dc=8, n=8); wave q handles channels 2q,2q+1; lane = d within chunk
__global__ __launch_bounds__(256) void attn_kernel(const float* __restrict__ cov,
                                                   const float* __restrict__ proj_w,
                                                   const float* __restrict__ proj_b,
                                                   const float* __restrict__ gvec_w,
                                                   float* __restrict__ gpart) {
    const int dc = blockIdx.x;
    const int n = blockIdx.y;
    const int tid = threadIdx.x;
    __shared__ float feat[8][FF];

    for (int f = tid; f < FF; f += 256) {
        const float* rec = cov + (size_t)(n * FF + f) * REC_STRIDE;
        float inv_mx = 1.0f / (rec[129] + EPSI);
        float sum_ms = rec[128] * inv_mx;
        float scale = inv_mx / (7.0f * fmaxf(sum_ms, EPSI));
#pragma unroll
        for (int i = 0; i < 8; i++) {
            float rr = 0.f, ri = 0.f;
#pragma unroll
            for (int j = 0; j < 8; j++) {
                if (j == i) continue;
                if (j > i) { rr += rec[PIDX(i, j)]; ri += rec[36 + QIDX(i, j)]; }
                else       { rr += rec[PIDX(j, i)]; ri -= rec[36 + QIDX(j, i)]; }
            }
            feat[i][f] = sqrtf(rr * rr + ri * ri) * scale;
        }
    }
    __syncthreads();

    const int wv = tid >> 6, lane = tid & 63;
    const int d = dc * 64 + lane;
    const int c0 = 2 * wv, c1 = c0 + 1;
    const float* pwd = proj_w + (size_t)d * FF;
    float a0 = proj_b[d], a1 = a0;
    for (int f = 0; f < FF; f++) {
        float w = pwd[f];
        a0 += w * feat[c0][f];
        a1 += w * feat[c1][f];
    }
    float gwd = gvec_w[d];
    float g0 = gwd * tanhf(a0);
    float g1 = gwd * tanhf(a1);
    g0 = wredsum(g0);
    g1 = wredsum(g1);
    if (!lane) {
        gpart[(n * 8 + dc) * 8 + c0] = g0;
        gpart[(n * 8 + dc) * 8 + c1] = g1;
    }
}

__global__ void attn2_kernel(const float* __restrict__ gpart, const float* __restrict__ gvec_b,
                             float* __restrict__ u) {
    const int n = blockIdx.x;
    const int lane = threadIdx.x;  // 64: dc*8 + c
    float v = gpart[n * 64 + lane];
    v += __shfl_xor(v, 8, 64);
    v += __shfl_xor(v, 16, 64);
    v += __shfl_xor(v, 32, 64);
    float g = v + gvec_b[0];
    float m = g;
    m = fmaxf(m, __shfl_xor(m, 1, 64));
    m = fmaxf(m, __shfl_xor(m, 2, 64));
    m = fmaxf(m, __shfl_xor(m, 4, 64));
    float e = expf(g - m);
    float s = e;
    s += __shfl_xor(s, 1, 64);
    s += __shfl_xor(s, 2, 64);
    s += __shfl_xor(s, 4, 64);
    if (lane < 8) u[n * 8 + lane] = e / s;
}

__global__ __launch_bounds__(64) void solve_kernel(const float* __restrict__ cov,
                                                   const float* __restrict__ u,
                                                   float* __restrict__ wout) {
    const int idx = blockIdx.x * 64 + threadIdx.x;
    if (idx >= NB * FF) return;
    const int n = idx / FF;
    const float* rec = cov + (size_t)idx * REC_STRIDE;

    float raw = rec[128], mx = rec[129];
    float inv_mx = 1.0f / (mx + EPSI);
    float sum_ms = raw * inv_mx;
    float inv_s = 1.0f / fmaxf(sum_ms, EPSI);
    float inv_n = 1.0f / fmaxf((float)TT - sum_ms, EPSI);
    float ks = inv_mx * inv_s;   // Rs entry scale on raw masked sums

    float Ar[8][8], Ai[8][8], Br[8][8], Bi[8][8];  // A = Rn, B = Rs -> X
#pragma unroll
    for (int i = 0; i < 8; i++) {
#pragma unroll
        for (int j = i; j < 8; j++) {
            float mr = rec[PIDX(i, j)];
            float tr = rec[64 + PIDX(i, j)];
            float s_r = mr * ks;
            float n_r = (tr - mr * inv_mx) * inv_n;
            if (j == i) {
                Br[i][i] = s_r; Bi[i][i] = 0.f;
                Ar[i][i] = n_r + EPS5; Ai[i][i] = 0.f;
            } else {
                float mi = rec[36 + QIDX(i, j)];
                float ti = rec[100 + QIDX(i, j)];
                float s_i = mi * ks;
                float n_i = (ti - mi * inv_mx) * inv_n;
                Br[i][j] = s_r; Bi[i][j] = s_i;
                Br[j][i] = s_r; Bi[j][i] = -s_i;
                Ar[i][j] = n_r; Ai[i][j] = n_i;
                Ar[j][i] = n_r; Ai[j][i] = -n_i;
            }
        }
    }

    // forward elimination (no pivot: A is HPD + eps*I)
#pragma unroll
    for (int k = 0; k < 8; k++) {
        float dr = Ar[k][k], di = Ai[k][k];
        float iv = 1.0f / (dr * dr + di * di);
        float pir = dr * iv, pii = -di * iv;
#pragma unroll
        for (int r = k + 1; r < 8; r++) {
            float ar = Ar[r][k], ai = Ai[r][k];
            float fr = ar * pir - ai * pii;
            float fi = ar * pii + ai * pir;
#pragma unroll
            for (int j = k + 1; j < 8; j++) {
                Ar[r][j] -= fr * Ar[k][j] - fi * Ai[k][j];
                Ai[r][j] -= fr * Ai[k][j] + fi * Ar[k][j];
            }
#pragma unroll
            for (int j = 0; j < 8; j++) {
                Br[r][j] -= fr * Br[k][j] - fi * Bi[k][j];
                Bi[r][j] -= fr * Bi[k][j] + fi * Br[k][j];
            }
        }
    }
    // back substitution
#pragma unroll
    for (int k = 7; k >= 0; k--) {
        float dr = Ar[k][k], di = Ai[k][k];
        float iv = 1.0f / (dr * dr + di * di);
        float pir = dr * iv, pii = -di * iv;
#pragma unroll
        for (int j = 0; j < 8; j++) {
            float s_r = Br[k][j], s_i = Bi[k][j];
#pragma unroll
            for (int m = k + 1; m < 8; m++) {
                s_r -= Ar[k][m] * Br[m][j] - Ai[k][m] * Bi[m][j];
                s_i -= Ar[k][m] * Bi[m][j] + Ai[k][m] * Br[m][j];
            }
            Br[k][j] = s_r * pir - s_i * pii;
            Bi[k][j] = s_r * pii + s_i * pir;
        }
    }

    float trr = EPS5, tri = 0.f;
#pragma unroll
    for (int i = 0; i < 8; i++) { trr += Br[i][i]; tri += Bi[i][i]; }
    float tinv = 1.0f / (trr * trr + tri * tri);

    float* wo = wout + (size_t)idx * 16;
#pragma unroll
    for (int i = 0; i < 8; i++) {
        float nr = 0.f, ni = 0.f;
#pragma unroll
        for (int c = 0; c < 8; c++) {
            float uc = u[n * 8 + c];
            nr += Br[i][c] * uc;
            ni += Bi[i][c] * uc;
        }
        float wr = (nr * trr + ni * tri) * tinv;
        float wi = (ni * trr - nr * tri) * tinv;
        wo[i * 2] = wr;        // store conj(w): real
        wo[i * 2 + 1] = -wi;   // store conj(w): imag
    }
}

__global__ __launch_bounds__(256) void beam_kernel(const float* __restrict__ xr,
                                                   const float* __restrict__ xi,
                                                   const float* __restrict__ wc,
                                                   float* __restrict__ out) {
    const int n = blockIdx.z;
    const int f0 = blockIdx.y * 32;
    const int t0 = blockIdx.x * 64;
    const int tid = threadIdx.x;

    __shared__ float wlds[32][16];
    __shared__ float bldr[32][65];
    __shared__ float bldi[32][65];

    for (int s = tid; s < 32 * 16; s += 256) {
        int fl = s >> 4, rest = s & 15;
        int f = f0 + fl;
        wlds[fl][rest] = (f < FF) ? wc[(size_t)(n * FF + f) * 16 + rest] : 0.f;
    }
    __syncthreads();

    const int lane_t = tid & 63, row = tid >> 6;
    const int t = t0 + lane_t;
    const bool tok = t < TT;
    const size_t cstride = (size_t)FF * TT;

#pragma unroll
    for (int k = 0; k < 8; k++) {
        int fl = row + k * 4;
        int f = f0 + fl;
        float br = 0.f, bi = 0.f;
        if (f < FF && tok) {
            size_t base = ((size_t)(n * CCH) * FF + f) * TT + t;
#pragma unroll
            for (int c = 0; c < 8; c++) {
                float vr = xr[base + c * cstride];
                float vi = xi[base + c * cstride];
                float wr = wlds[fl][c * 2], wi_ = wlds[fl][c * 2 + 1];
                br += wr * vr - wi_ * vi;
                bi += wr * vi + wi_ * vr;
            }
        }
        bldr[fl][lane_t] = br;
        bldi[fl][lane_t] = bi;
    }
    __syncthreads();

    const int fc = tid & 31, trb = tid >> 5;
    const int f = f0 + fc;
    float2* outv = (float2*)out;
#pragma unroll
    for (int k = 0; k < 8; k++) {
        int tr = trb + k * 8;
        int t2 = t0 + tr;
        if (f < FF && t2 < TT) {
            float2 v = make_float2(bldr[fc][tr], bldi[fc][tr]);
            outv[(size_t)(n * TT + t2) * FF + f] = v;
        }
    }
}

extern "C" void kernel_launch(void* const* d_in, const int* in_sizes, int n_in,
                              void* d_out, int out_size, void* d_ws, size_t ws_size,
                              hipStream_t stream) {
    const float* mask = (const float*)d_in[0];
    const float* xr = (const float*)d_in[1];
    const float* xi = (const float*)d_in[2];
    const float* pw = (const float*)d_in[3];
    const float* pb = (const float*)d_in[4];
    const float* gw = (const float*)d_in[5];
    const float* gb = (const float*)d_in[6];
    float* out = (float*)d_out;
    float* ws = (float*)d_ws;

    float* maskT = ws;                                           // 8*257*1000
    float* cov = maskT + (size_t)NB * FF * TT;                   // 2056*132
    float* gpart = cov + (size_t)NB * FF * REC_STRIDE;           // 512
    float* u = gpart + 512;                                      // 64
    float* wv = u + 64;                                          // 2056*16

    hipLaunchKernelGGL(mask_transpose_kernel, dim3((FF + 31) / 32, (TT + 31) / 32, NB), dim3(256), 0, stream, mask, maskT);
    hipLaunchKernelGGL(cov_kernel, dim3(4, FF, NB), dim3(256), 0, stream, maskT, xr, xi, cov);
    hipLaunchKernelGGL(attn_kernel, dim3(8, NB), dim3(256), 0, stream, cov, pw, pb, gw, gpart);
    hipLaunchKernelGGL(attn2_kernel, dim3(NB), dim3(64), 0, stream, gpart, gb, u);
    hipLaunchKernelGGL(solve_kernel, dim3((NB * FF + 63) / 64), dim3(64), 0, stream, cov, u, wv);
    hipLaunchKernelGGL(beam_kernel, dim3((TT + 63) / 64, (FF + 31) / 32, NB), dim3(256), 0, stream, xr, xi, wv, out);
}